// Round 3
// baseline (4303.133 us; speedup 1.0000x reference)
//
#include <hip/hip_runtime.h>
#include <cstdint>

#define D 300
#define HP 304     // padded f32 row stride for h/h2 (1216B = 19 cache lines)
#define MAXLEN 50
#define K1P 320    // padded K for gemm1 (agg cols)
#define H1 600     // hidden dim
#define H1P 608    // padded hidden (gemm2 K)
#define W1ROWS 640 // padded Nout rows for W1t (10 col-tiles of 64)
#define W2ROWS 384 // padded Nout rows for W2t (8 col-tiles of 48)

typedef __attribute__((ext_vector_type(8))) short s16x8;
typedef __attribute__((ext_vector_type(4))) float f32x4;

__device__ __forceinline__ unsigned short f2b(float f) {
  uint32_t u = __builtin_bit_cast(uint32_t, f);
  u += 0x7FFFu + ((u >> 16) & 1u);
  return (unsigned short)(u >> 16);
}

// ---------------- embedding: h0 = x_emb1[x0] + x_emb2[x1], stride HP ----------------
__global__ void k_embed(const int* __restrict__ x, const float* __restrict__ xe1,
                        const float* __restrict__ xe2, float* __restrict__ h, int total) {
  int i = blockIdx.x * blockDim.x + threadIdx.x;
  if (i >= total) return;
  int row = i / 75, d = (i - row * 75) * 4;
  int a = x[2 * row], b = x[2 * row + 1];
  const float* p1 = xe1 + (size_t)a * D + d;
  const float* p2 = xe2 + (size_t)b * D + d;
  f32x4 v;
#pragma unroll
  for (int k = 0; k < 4; ++k) v[k] = p1[k] + p2[k];
  *(f32x4*)(h + (size_t)row * HP + d) = v;
}

// zero K-pad columns of aggbf [N][320] (300..319) and hid [N][608] (600..607)
__global__ void k_padfill(unsigned short* __restrict__ aggbf, unsigned short* __restrict__ hid, int N) {
  int idx = blockIdx.x * blockDim.x + threadIdx.x;
  if (idx >= N * 28) return;
  int i = idx / 28, j = idx - i * 28;
  if (j < 20) aggbf[(size_t)i * K1P + D + j] = 0;
  else        hid[(size_t)i * H1P + H1 + (j - 20)] = 0;
}

__global__ void k_count(const int* __restrict__ key, int* __restrict__ cnt, int n) {
  int i = blockIdx.x * blockDim.x + threadIdx.x;
  if (i < n) atomicAdd(&cnt[key[i]], 1);
}

__global__ void k_exscan(const int* __restrict__ in, int* __restrict__ out, int n) {
  __shared__ int smem[1024];
  int tid = threadIdx.x;
  int chunk = (n + 1023) >> 10;
  int beg = tid * chunk;
  int end = beg + chunk; if (end > n) end = n;
  int s = 0;
  for (int i = beg; i < end; ++i) s += in[i];
  smem[tid] = s;
  __syncthreads();
  for (int off = 1; off < 1024; off <<= 1) {
    int v = (tid >= off) ? smem[tid - off] : 0;
    __syncthreads();
    smem[tid] += v;
    __syncthreads();
  }
  int run = smem[tid] - s;
  for (int i = beg; i < end; ++i) { out[i] = run; run += in[i]; }
  if (tid == 1023) out[n] = smem[1023];
}

__global__ void k_fill(const int* __restrict__ src, const int* __restrict__ dst,
                       const int* __restrict__ ea, int* __restrict__ cur,
                       const int* __restrict__ offs, int* __restrict__ ssrc,
                       int* __restrict__ seco, int E_) {
  int e = blockIdx.x * blockDim.x + threadIdx.x;
  if (e >= E_) return;
  int d = dst[e];
  int p = atomicAdd(&cur[d], 1);
  int pos = offs[d] + p;
  ssrc[pos] = src[e];
  seco[pos] = ea[2 * e] * 3 + ea[2 * e + 1];
}

// combined edge-emb table: ec[l][c0*3+c1][d] = e1[l][c0][d] + e2[l][c1][d]
__global__ void k_ecomb(const float* __restrict__ e1, const float* __restrict__ e2,
                        float* __restrict__ ec, int total) {
  int i = blockIdx.x * blockDim.x + threadIdx.x;
  if (i >= total) return;
  int d = i % D;
  int c = (i / D) % 18;
  int l = i / (18 * D);
  int c0 = c / 3, c1 = c - c0 * 3;
  ec[i] = e1[((size_t)l * 6 + c0) * D + d] + e2[((size_t)l * 3 + c1) * D + d];
}

// ---------------- aggregation: one wave per node; optional fused BN+ReLU on input ----------------
template <int FUSE>
__global__ void k_agg(const float* __restrict__ hin, const int* __restrict__ ssrc,
                      const int* __restrict__ seco, const int* __restrict__ offs,
                      const float* __restrict__ ec, const float* __restrict__ scale,
                      const float* __restrict__ shift, unsigned short* __restrict__ aggbf, int N) {
  int w = (int)((blockIdx.x * blockDim.x + threadIdx.x) >> 6);
  if (w >= N) return;
  int lane = threadIdx.x & 63;
  float sc[5], sh[5];
  if (FUSE) {
#pragma unroll
    for (int i = 0; i < 5; ++i) {
      int d = i * 64 + lane;
      sc[i] = (d < D) ? scale[d] : 0.f;
      sh[i] = (d < D) ? shift[d] : 0.f;
    }
  }
  int beg = offs[w], end = offs[w + 1];
  float s[5];
#pragma unroll
  for (int i = 0; i < 5; ++i) {
    int d = i * 64 + lane;
    float v = 0.f;
    if (d < D) {
      v = hin[(size_t)w * HP + d];
      if (FUSE) v = fmaxf(v * sc[i] + sh[i], 0.f);
      v += ec[12 * D + d];  // self loop: bond=4,dir=0 -> combo 12
    }
    s[i] = v;
  }
  for (int j = beg; j < end; ++j) {
    int sv = ssrc[j], co = seco[j];
    const float* hp = hin + (size_t)sv * HP;
    const float* tp = ec + (size_t)co * D;
#pragma unroll
    for (int i = 0; i < 5; ++i) {
      int d = i * 64 + lane;
      if (d < D) {
        float v = hp[d];
        if (FUSE) v = fmaxf(v * sc[i] + sh[i], 0.f);
        s[i] += v + tp[d];
      }
    }
  }
#pragma unroll
  for (int i = 0; i < 5; ++i) {
    int d = i * 64 + lane;
    if (d < D) aggbf[(size_t)w * K1P + d] = f2b(s[i]);
  }
}

// transpose+convert weights: Wt[n][k] = bf16(W[k][n]), zero-padded
__global__ void k_wconv(const float* __restrict__ W, unsigned short* __restrict__ Wt,
                        int K, int Nout, int Kp, int total) {
  int idx = blockIdx.x * blockDim.x + threadIdx.x;
  if (idx >= total) return;
  int n = idx / Kp, k = idx - n * Kp;
  float v = (k < K && n < Nout) ? W[(size_t)k * Nout + n] : 0.f;
  Wt[idx] = f2b(v);
}

// ---------------- B-resident-LDS streaming bf16 MFMA GEMM ----------------
// Block: 4 waves stacked over rows; each wave = 64 rows x NC cols; B col-panel
// staged in LDS once (XOR slot swizzle, conflict-free); A streamed from global;
// block loops over row-tiles (stride RB). No barriers in the main loop.
// EPI=1: relu -> bf16 store. EPI=0: f32 store + BN stats in regs -> atomics at end.
template <int K, int NC, int EPI>
__global__ __launch_bounds__(256, (NC == 64 ? 4 : 2)) void k_gemm(
    const unsigned short* __restrict__ A, const unsigned short* __restrict__ Bt,
    const float* __restrict__ bias, unsigned short* __restrict__ Cb,
    float* __restrict__ Cf, float* __restrict__ sums,
    int M, int Nout, int ldc, int CT, int RB) {
  constexpr int T = K / 32;
  constexpr int NI = NC / 16;
  constexpr int KD8 = K / 8;
  __shared__ __align__(16) unsigned short Bl[T * NC * 32];

  // bijective XCD-chunk swizzle (grid is a multiple of 8): consecutive wids
  // (same rb, all ct) land on one XCD -> shared A panel in its L2.
  int cpx = (CT * RB) >> 3;
  int wid = (blockIdx.x & 7) * cpx + (blockIdx.x >> 3);
  int ct = wid % CT, rb = wid / CT;

  const int tid = threadIdx.x, lane = tid & 63, wave = tid >> 6;
  const int l15 = lane & 15, lg = lane >> 4;

  // stage B panel: cols [ct*NC, ct*NC+NC), layout [t][c][slot^swz]*16B
  const unsigned short* Bsrc = Bt + (size_t)ct * NC * K;
  for (int u = tid; u < NC * KD8; u += 256) {
    int c = u / KD8, v = u - c * KD8;
    int t = v >> 2, kw = v & 3;
    s16x8 tmp = *(const s16x8*)(Bsrc + (size_t)c * K + v * 8);
    *(s16x8*)(Bl + ((size_t)(t * NC + c) * 4 + (kw ^ ((c >> 1) & 3))) * 8) = tmp;
  }
  __syncthreads();

  int bOff[NI];
#pragma unroll
  for (int ni = 0; ni < NI; ++ni) {
    int c = ni * 16 + l15;
    bOff[ni] = (c * 4 + (lg ^ ((c >> 1) & 3))) * 8;
  }

  float bnS[NI], bnQ[NI];
#pragma unroll
  for (int ni = 0; ni < NI; ++ni) { bnS[ni] = 0.f; bnQ[ni] = 0.f; }

  const int RT = (M + 255) >> 8;
  for (int rt = rb; rt < RT; rt += RB) {
    int rowBase = rt * 256 + wave * 64;
    const unsigned short* Ap[4];
#pragma unroll
    for (int mi = 0; mi < 4; ++mi) {
      int rr = rowBase + mi * 16 + l15;
      if (rr >= M) rr = M - 1;
      Ap[mi] = A + (size_t)rr * K + lg * 8;
    }
    f32x4 acc[4][NI] = {};
#pragma unroll
    for (int t = 0; t < T; ++t) {
      s16x8 af[4], bf[NI];
#pragma unroll
      for (int mi = 0; mi < 4; ++mi) af[mi] = *(const s16x8*)(Ap[mi] + t * 32);
#pragma unroll
      for (int ni = 0; ni < NI; ++ni) bf[ni] = *(const s16x8*)(Bl + (size_t)t * NC * 32 + bOff[ni]);
#pragma unroll
      for (int mi = 0; mi < 4; ++mi)
#pragma unroll
        for (int ni = 0; ni < NI; ++ni)
          acc[mi][ni] = __builtin_amdgcn_mfma_f32_16x16x32_bf16(af[mi], bf[ni], acc[mi][ni], 0, 0, 0);
    }
#pragma unroll
    for (int ni = 0; ni < NI; ++ni) {
      int col = ct * NC + ni * 16 + l15;
      if (col >= Nout) continue;
      float bv = bias[col];
#pragma unroll
      for (int mi = 0; mi < 4; ++mi) {
        int row0 = rowBase + mi * 16 + lg * 4;
#pragma unroll
        for (int r = 0; r < 4; ++r) {
          int row = row0 + r;
          if (row < M) {
            float v = acc[mi][ni][r] + bv;
            if (EPI) {
              v = fmaxf(v, 0.f);
              Cb[(size_t)row * ldc + col] = f2b(v);
            } else {
              Cf[(size_t)row * ldc + col] = v;
              bnS[ni] += v;
              bnQ[ni] += v * v;
            }
          }
        }
      }
    }
  }
  if (!EPI) {
#pragma unroll
    for (int ni = 0; ni < NI; ++ni) {
      float cs = bnS[ni], cq = bnQ[ni];
      cs += __shfl_xor(cs, 16); cq += __shfl_xor(cq, 16);
      cs += __shfl_xor(cs, 32); cq += __shfl_xor(cq, 32);
      int col = ct * NC + ni * 16 + l15;
      if (lg == 0 && col < Nout) {
        atomicAdd(&sums[col], cs);
        atomicAdd(&sums[D + col], cq);
      }
    }
  }
}

// ---------------- BatchNorm finalize ----------------
__global__ void k_bnfinal(const float* __restrict__ sums, const float* __restrict__ sumsq,
                          const float* __restrict__ gamma, const float* __restrict__ beta,
                          float* __restrict__ scale, float* __restrict__ shift, int N) {
  int c = threadIdx.x;
  if (c >= D) return;
  float inv = 1.f / (float)N;
  float mean = sums[c] * inv;
  float var = sumsq[c] * inv - mean * mean;
  if (var < 0.f) var = 0.f;
  float sc = gamma[c] * rsqrtf(var + 1e-5f);
  scale[c] = sc;
  shift[c] = beta[c] - mean * sc;
}

// materialize h = bn(h2) (no relu) for the last layer only
__global__ void k_bnnorm(const float* __restrict__ h2, const float* __restrict__ scale,
                         const float* __restrict__ shift, float* __restrict__ h, int total) {
  int i = blockIdx.x * blockDim.x + threadIdx.x;
  if (i >= total) return;
  int row = i / 75, d = (i - row * 75) * 4;
  f32x4 v = *(const f32x4*)(h2 + (size_t)row * HP + d);
#pragma unroll
  for (int k = 0; k < 4; ++k) v[k] = v[k] * scale[d + k] + shift[d + k];
  *(f32x4*)(h + (size_t)row * HP + d) = v;
}

// ---------------- outputs ----------------
__global__ void k_pool(const float* __restrict__ h, const int* __restrict__ gs,
                       const int* __restrict__ gc, float* __restrict__ pooled) {
  int g = blockIdx.x, c = threadIdx.x;
  if (c >= D) return;
  int start = gs[g], cnt = gc[g];
  float s = 0.f;
  for (int i = 0; i < cnt; ++i) s += h[(size_t)(start + i) * HP + c];
  int dv = cnt > 0 ? cnt : 1;
  pooled[(size_t)g * D + c] = s / (float)dv;
}

__global__ void k_nf(const float* __restrict__ h, const int* __restrict__ gs,
                     const int* __restrict__ gc, float* __restrict__ nf, float* __restrict__ mask) {
  int g = blockIdx.x;
  int start = gs[g], cnt = gc[g];
  int lim = cnt < MAXLEN ? cnt : MAXLEN;
  for (int idx = threadIdx.x; idx < MAXLEN * D; idx += 256) {
    int p = idx / D;
    int c = idx - p * D;
    float v = (p < lim) ? h[(size_t)(start + p) * HP + c] : 0.f;
    nf[(size_t)g * (MAXLEN * D) + idx] = v;
  }
  if (threadIdx.x < MAXLEN) mask[(size_t)g * MAXLEN + threadIdx.x] = (threadIdx.x < lim) ? 1.f : 0.f;
}

extern "C" void kernel_launch(void* const* d_in, const int* in_sizes, int n_in,
                              void* d_out, int out_size, void* d_ws, size_t ws_size,
                              hipStream_t stream) {
  const int* x      = (const int*)d_in[0];
  const int* ei     = (const int*)d_in[1];   // [2][E]: src = ei, dst = ei+E
  const int* ea     = (const int*)d_in[2];   // [E][2]
  const int* batch  = (const int*)d_in[3];
  const float* xe1  = (const float*)d_in[5];
  const float* xe2  = (const float*)d_in[6];
  const float* ee1  = (const float*)d_in[7]; // [L][6][D]
  const float* ee2  = (const float*)d_in[8]; // [L][3][D]
  const float* W1   = (const float*)d_in[9];
  const float* b1   = (const float*)d_in[10];
  const float* W2   = (const float*)d_in[11];
  const float* b2   = (const float*)d_in[12];
  const float* gamma = (const float*)d_in[13];
  const float* beta  = (const float*)d_in[14];

  const int N = in_sizes[0] / 2;
  const int E = in_sizes[1] / 2;
  const int L = in_sizes[9] / (D * 2 * D);
  const int B = out_size / (D + MAXLEN * D + MAXLEN);

  char* ws = (char*)d_ws;
  size_t off = 0;
  auto alloc = [&](size_t bytes) -> void* {
    void* p = ws + off;
    off += (bytes + 255) & ~(size_t)255;
    return p;
  };
  float* h   = (float*)alloc((size_t)N * HP * 4);
  float* h2  = (float*)alloc((size_t)N * HP * 4);
  unsigned short* aggbf = (unsigned short*)alloc((size_t)N * K1P * 2);
  unsigned short* hid   = (unsigned short*)alloc((size_t)N * H1P * 2);
  unsigned short* W1tA = (unsigned short*)alloc((size_t)L * W1ROWS * K1P * 2);
  unsigned short* W2tA = (unsigned short*)alloc((size_t)L * W2ROWS * H1P * 2);
  float* ecomb = (float*)alloc((size_t)L * 18 * D * 4);
  int* cnt    = (int*)alloc((size_t)N * 4);
  int* cur    = (int*)alloc((size_t)N * 4);
  int* offs   = (int*)alloc((size_t)(N + 1) * 4);
  int* ssrc   = (int*)alloc((size_t)E * 4);
  int* seco   = (int*)alloc((size_t)E * 4);
  int* gc     = (int*)alloc((size_t)B * 4);
  int* gs     = (int*)alloc((size_t)(B + 1) * 4);
  float* sums  = (float*)alloc(2 * D * 4);  // sums | sumsq
  float* scale = (float*)alloc(2 * D * 4);  // scale | shift

  hipMemsetAsync(cnt, 0, (size_t)N * 4, stream);
  hipMemsetAsync(cur, 0, (size_t)N * 4, stream);
  hipMemsetAsync(gc, 0, (size_t)B * 4, stream);

  const int nh = N * 75;
  k_embed<<<(nh + 255) / 256, 256, 0, stream>>>(x, xe1, xe2, h, nh);
  k_padfill<<<(N * 28 + 255) / 256, 256, 0, stream>>>(aggbf, hid, N);
  k_count<<<(E + 255) / 256, 256, 0, stream>>>(ei + E, cnt, E);
  k_exscan<<<1, 1024, 0, stream>>>(cnt, offs, N);
  k_fill<<<(E + 255) / 256, 256, 0, stream>>>(ei, ei + E, ea, cur, offs, ssrc, seco, E);
  k_count<<<(N + 255) / 256, 256, 0, stream>>>(batch, gc, N);
  k_exscan<<<1, 1024, 0, stream>>>(gc, gs, B);
  k_ecomb<<<(L * 18 * D + 255) / 256, 256, 0, stream>>>(ee1, ee2, ecomb, L * 18 * D);
  for (int l = 0; l < L; ++l) {
    k_wconv<<<(W1ROWS * K1P + 255) / 256, 256, 0, stream>>>(
        W1 + (size_t)l * D * H1, W1tA + (size_t)l * W1ROWS * K1P, D, H1, K1P, W1ROWS * K1P);
    k_wconv<<<(W2ROWS * H1P + 255) / 256, 256, 0, stream>>>(
        W2 + (size_t)l * H1 * D, W2tA + (size_t)l * W2ROWS * H1P, H1, D, H1P, W2ROWS * H1P);
  }

  for (int l = 0; l < L; ++l) {
    if (l == 0)
      k_agg<0><<<(N + 3) / 4, 256, 0, stream>>>(h, ssrc, seco, offs,
          ecomb + (size_t)l * 18 * D, nullptr, nullptr, aggbf, N);
    else
      k_agg<1><<<(N + 3) / 4, 256, 0, stream>>>(h2, ssrc, seco, offs,
          ecomb + (size_t)l * 18 * D, scale, scale + D, aggbf, N);
    k_gemm<K1P, 64, 1><<<480, 256, 0, stream>>>(
        aggbf, W1tA + (size_t)l * W1ROWS * K1P, b1 + (size_t)l * H1, hid, nullptr, nullptr,
        N, H1, H1P, 10, 48);
    hipMemsetAsync(sums, 0, 2 * D * 4, stream);
    k_gemm<H1P, 48, 0><<<480, 256, 0, stream>>>(
        hid, W2tA + (size_t)l * W2ROWS * H1P, b2 + (size_t)l * D, nullptr, h2, sums,
        N, D, HP, 8, 60);
    k_bnfinal<<<1, 320, 0, stream>>>(sums, sums + D, gamma + (size_t)l * D, beta + (size_t)l * D,
                                     scale, scale + D, N);
  }
  k_bnnorm<<<(nh + 255) / 256, 256, 0, stream>>>(h2, scale, scale + D, h, nh);

  float* out = (float*)d_out;
  float* out_pooled = out;
  float* out_nf = out + (size_t)B * D;
  float* out_mask = out + (size_t)B * D + (size_t)B * MAXLEN * D;
  k_pool<<<B, 320, 0, stream>>>(h, gs, gc, out_pooled);
  k_nf<<<B, 256, 0, stream>>>(h, gs, gc, out_nf, out_mask);
}

// Round 5
// 2737.664 us; speedup vs baseline: 1.5718x; 1.5718x over previous
//
#include <hip/hip_runtime.h>
#include <cstdint>

#define D 300
#define HP 304     // padded f32 row stride for h (1216B = 19 cache lines)
#define MAXLEN 50
#define K1P 320    // bf16 row stride for r/aggbf/hb (640B = 10 lines); gemm1 K
#define H1 600     // hidden dim
#define H1P 608    // hid bf16 row stride (1216B); gemm2 K
#define W1ROWS 640 // padded rows for W1t (5 col-tiles of 128)
#define W2ROWS 384 // padded rows for W2t (3 col-tiles of 128)

typedef __attribute__((ext_vector_type(8))) short s16x8;
typedef __attribute__((ext_vector_type(4))) short s16x4;
typedef __attribute__((ext_vector_type(4))) float f32x4;
typedef __attribute__((ext_vector_type(2))) float f32x2;

__device__ __forceinline__ unsigned short f2b(float f) {
  uint32_t u = __builtin_bit_cast(uint32_t, f);
  u += 0x7FFFu + ((u >> 16) & 1u);
  return (unsigned short)(u >> 16);
}
__device__ __forceinline__ float b2f(unsigned short s) {
  return __builtin_bit_cast(float, (uint32_t)s << 16);
}
__device__ __forceinline__ void gld_lds16(const void* g, void* l) {
  __builtin_amdgcn_global_load_lds((const __attribute__((address_space(1))) void*)g,
                                   (__attribute__((address_space(3))) void*)l, 16, 0, 0);
}

// ---------------- embedding -> bf16 r ----------------
__global__ void k_embed(const int* __restrict__ x, const float* __restrict__ xe1,
                        const float* __restrict__ xe2, unsigned short* __restrict__ r, int total) {
  int i = blockIdx.x * blockDim.x + threadIdx.x;
  if (i >= total) return;
  int row = i / 75, d = (i - row * 75) * 4;
  int a = x[2 * row], b = x[2 * row + 1];
  s16x4 out;
#pragma unroll
  for (int j = 0; j < 4; ++j) out[j] = (short)f2b(xe1[(size_t)a * D + d + j] + xe2[(size_t)b * D + d + j]);
  *(s16x4*)(r + (size_t)row * K1P + d) = out;
}

// zero K-pad cols 300..319 of aggbf
__global__ void k_padfill(unsigned short* __restrict__ aggbf, int N) {
  int idx = blockIdx.x * blockDim.x + threadIdx.x;
  if (idx >= N * 10) return;
  int i = idx / 10, j = idx - i * 10;
  *(uint32_t*)(aggbf + (size_t)i * K1P + D + j * 2) = 0;
}

__global__ void k_count(const int* __restrict__ key, int* __restrict__ cnt, int n) {
  int i = blockIdx.x * blockDim.x + threadIdx.x;
  if (i < n) atomicAdd(&cnt[key[i]], 1);
}

__global__ void k_exscan(const int* __restrict__ in, int* __restrict__ out, int n) {
  __shared__ int smem[1024];
  int tid = threadIdx.x;
  int chunk = (n + 1023) >> 10;
  int beg = tid * chunk;
  int end = beg + chunk; if (end > n) end = n;
  int s = 0;
  for (int i = beg; i < end; ++i) s += in[i];
  smem[tid] = s;
  __syncthreads();
  for (int off = 1; off < 1024; off <<= 1) {
    int v = (tid >= off) ? smem[tid - off] : 0;
    __syncthreads();
    smem[tid] += v;
    __syncthreads();
  }
  int run = smem[tid] - s;
  for (int i = beg; i < end; ++i) { out[i] = run; run += in[i]; }
  if (tid == 1023) out[n] = smem[1023];
}

__global__ void k_fill(const int* __restrict__ src, const int* __restrict__ dst,
                       const int* __restrict__ ea, int* __restrict__ cur,
                       const int* __restrict__ offs, int* __restrict__ ssrc,
                       int* __restrict__ seco, int E_) {
  int e = blockIdx.x * blockDim.x + threadIdx.x;
  if (e >= E_) return;
  int d = dst[e];
  int p = atomicAdd(&cur[d], 1);
  int pos = offs[d] + p;
  ssrc[pos] = src[e];
  seco[pos] = ea[2 * e] * 3 + ea[2 * e + 1];
}

// combined edge-emb table: ec[l][c0*3+c1][d]
__global__ void k_ecomb(const float* __restrict__ e1, const float* __restrict__ e2,
                        float* __restrict__ ec, int total) {
  int i = blockIdx.x * blockDim.x + threadIdx.x;
  if (i >= total) return;
  int d = i % D;
  int c = (i / D) % 18;
  int l = i / (18 * D);
  int c0 = c / 3, c1 = c - c0 * 3;
  ec[i] = e1[((size_t)l * 6 + c0) * D + d] + e2[((size_t)l * 3 + c1) * D + d];
}

// ---------------- aggregation: one wave per node; bf16 gathers ----------------
__global__ void k_agg(const unsigned short* __restrict__ r, const int* __restrict__ ssrc,
                      const int* __restrict__ seco, const int* __restrict__ offs,
                      const float* __restrict__ ec, unsigned short* __restrict__ aggbf, int N) {
  int w = (int)((blockIdx.x * blockDim.x + threadIdx.x) >> 6);
  if (w >= N) return;
  int lane = threadIdx.x & 63;
  int beg = offs[w], end = offs[w + 1];
  float s0[3], s1[3];
#pragma unroll
  for (int i = 0; i < 3; ++i) {
    int d2 = i * 64 + lane;
    float a = 0.f, b = 0.f;
    if (d2 < 150) {
      uint32_t u = *(const uint32_t*)(r + (size_t)w * K1P + d2 * 2);
      f32x2 e = *(const f32x2*)(ec + 12 * D + d2 * 2);  // self loop combo 12
      a = __builtin_bit_cast(float, u << 16) + e[0];
      b = __builtin_bit_cast(float, u & 0xFFFF0000u) + e[1];
    }
    s0[i] = a; s1[i] = b;
  }
  for (int j = beg; j < end; ++j) {
    int sv = ssrc[j], co = seco[j];
    const unsigned short* rp = r + (size_t)sv * K1P;
    const float* tp = ec + (size_t)co * D;
#pragma unroll
    for (int i = 0; i < 3; ++i) {
      int d2 = i * 64 + lane;
      if (d2 < 150) {
        uint32_t u = *(const uint32_t*)(rp + d2 * 2);
        f32x2 e = *(const f32x2*)(tp + d2 * 2);
        s0[i] += __builtin_bit_cast(float, u << 16) + e[0];
        s1[i] += __builtin_bit_cast(float, u & 0xFFFF0000u) + e[1];
      }
    }
  }
#pragma unroll
  for (int i = 0; i < 3; ++i) {
    int d2 = i * 64 + lane;
    if (d2 < 150) {
      uint32_t o = (uint32_t)f2b(s0[i]) | ((uint32_t)f2b(s1[i]) << 16);
      *(uint32_t*)(aggbf + (size_t)w * K1P + d2 * 2) = o;
    }
  }
}

// transpose+convert weights: Wt[n][k] = bf16(W[k][n]), zero-padded
__global__ void k_wconv(const float* __restrict__ W, unsigned short* __restrict__ Wt,
                        int K, int Nout, int Kp, int total) {
  int idx = blockIdx.x * blockDim.x + threadIdx.x;
  if (idx >= total) return;
  int n = idx / Kp, k = idx - n * Kp;
  float v = (k < K && n < Nout) ? W[(size_t)k * Nout + n] : 0.f;
  Wt[idx] = f2b(v);
}

// ---------------- 2-phase double-buffered MFMA GEMM, bf16 out via LDS repack ----------------
// 128x128 tile, 4 waves (2x2), BK=32, global_load_lds staging one step ahead.
// EPI=1: relu. EPI=0: fused BN column stats (f32 accum) -> atomics.
template <int K, int EPI>
__global__ __launch_bounds__(256, 5) void k_gemm(
    const unsigned short* __restrict__ A, const unsigned short* __restrict__ Bt,
    const float* __restrict__ bias, unsigned short* __restrict__ Cb,
    float* __restrict__ sums, int M, int Nout, int ldc, int CT) {
  constexpr int T = K / 32;
  __shared__ __align__(16) unsigned short smem[16384];  // A dbuf 8K shorts | B dbuf 8K; reused as C[128][128]

  int nwg = gridDim.x;
  int q = nwg >> 3, r8 = nwg & 7;
  int xcd = blockIdx.x & 7, oidx = blockIdx.x >> 3;
  int wid = (xcd < r8 ? xcd * (q + 1) : r8 * (q + 1) + (xcd - r8) * q) + oidx;
  int ct = wid % CT, rt = wid / CT;
  const int rowBase = rt * 128, colBase = ct * 128;

  const int tid = threadIdx.x, lane = tid & 63, wave = tid >> 6;
  const int wm = wave >> 1, wn = wave & 1;
  const int l15 = lane & 15, lg = lane >> 4;

  unsigned short* Abuf = smem;         // [2][128 rows][32 k]
  unsigned short* Bbuf = smem + 8192;  // [2][128 rows][32 k]

  auto stage = [&](int b, int t) {
#pragma unroll
    for (int i = 0; i < 2; ++i) {
      int u = tid + i * 256;
      int rr = u >> 2, kw = u & 3;  // 4 lanes = one row's 64B chunk (coalesced)
      int gr = rowBase + rr; if (gr >= M) gr = M - 1;
      gld_lds16(A + (size_t)gr * K + t * 32 + kw * 8, Abuf + b * 4096 + u * 8);
      gld_lds16(Bt + (size_t)(colBase + rr) * K + t * 32 + kw * 8, Bbuf + b * 4096 + u * 8);
    }
  };

  f32x4 acc[4][4] = {};
  stage(0, 0);
  __syncthreads();
  for (int t = 0; t < T; ++t) {
    int b = t & 1;
    if (t + 1 < T) stage(b ^ 1, t + 1);  // async prefetch, in flight during compute
    const unsigned short* bA = Abuf + b * 4096;
    const unsigned short* bB = Bbuf + b * 4096;
    s16x8 af[4], bf[4];
#pragma unroll
    for (int i = 0; i < 4; ++i) {
      af[i] = *(const s16x8*)(bA + (wm * 64 + i * 16 + l15) * 32 + lg * 8);
      bf[i] = *(const s16x8*)(bB + (wn * 64 + i * 16 + l15) * 32 + lg * 8);
    }
#pragma unroll
    for (int mi = 0; mi < 4; ++mi)
#pragma unroll
      for (int ni = 0; ni < 4; ++ni)
        acc[mi][ni] = __builtin_amdgcn_mfma_f32_16x16x32_bf16(af[mi], bf[ni], acc[mi][ni], 0, 0, 0);
    __syncthreads();
  }

  // epilogue: bias (+relu / +BN stats), repack via LDS, coalesced 16B stores
  float bnS[4] = {0.f, 0.f, 0.f, 0.f}, bnQ[4] = {0.f, 0.f, 0.f, 0.f};
#pragma unroll
  for (int ni = 0; ni < 4; ++ni) {
    int gcol = colBase + wn * 64 + ni * 16 + l15;
    float bv = (gcol < Nout) ? bias[gcol] : 0.f;
#pragma unroll
    for (int mi = 0; mi < 4; ++mi) {
#pragma unroll
      for (int rr = 0; rr < 4; ++rr) {
        int lrow = wm * 64 + mi * 16 + lg * 4 + rr;
        float v = 0.f;
        if (gcol < Nout) {
          v = acc[mi][ni][rr] + bv;
          if (EPI) v = fmaxf(v, 0.f);
          else if (rowBase + lrow < M) { bnS[ni] += v; bnQ[ni] += v * v; }
        }
        smem[lrow * 128 + wn * 64 + ni * 16 + l15] = f2b(v);
      }
    }
  }
  __syncthreads();
#pragma unroll
  for (int i = 0; i < 8; ++i) {  // 2048 stores: full 128x128 tile (was i<2 = only 32 rows -> R4 bug)
    int u = tid + i * 256;
    int lrow = u >> 4, c16 = u & 15;
    int grow = rowBase + lrow, gcs = colBase + c16 * 8;
    if (grow < M && gcs < ldc)
      *(s16x8*)(Cb + (size_t)grow * ldc + gcs) = *(const s16x8*)(smem + lrow * 128 + c16 * 8);
  }
  if (!EPI) {
#pragma unroll
    for (int ni = 0; ni < 4; ++ni) {
      float cs = bnS[ni], cq = bnQ[ni];
      cs += __shfl_xor(cs, 16); cq += __shfl_xor(cq, 16);
      cs += __shfl_xor(cs, 32); cq += __shfl_xor(cq, 32);
      int gcol = colBase + wn * 64 + ni * 16 + l15;
      if (lg == 0 && gcol < Nout) {
        atomicAdd(&sums[gcol], cs);
        atomicAdd(&sums[D + gcol], cq);
      }
    }
  }
}

// ---------------- BatchNorm finalize ----------------
__global__ void k_bnfinal(const float* __restrict__ sums, const float* __restrict__ sumsq,
                          const float* __restrict__ gamma, const float* __restrict__ beta,
                          float* __restrict__ scale, float* __restrict__ shift, int N) {
  int c = threadIdx.x;
  if (c >= D) return;
  float inv = 1.f / (float)N;
  float mean = sums[c] * inv;
  float var = sumsq[c] * inv - mean * mean;
  if (var < 0.f) var = 0.f;
  float sc = gamma[c] * rsqrtf(var + 1e-5f);
  scale[c] = sc;
  shift[c] = beta[c] - mean * sc;
}

// r = bf16(relu(bn(hb)))  [layers 0..L-2]
__global__ void k_relubn(const unsigned short* __restrict__ hb, const float* __restrict__ scale,
                         const float* __restrict__ shift, unsigned short* __restrict__ r, int total) {
  int idx = blockIdx.x * blockDim.x + threadIdx.x;
  if (idx >= total) return;
  int row = idx / 40, c16 = idx - row * 40;
  int c0 = c16 * 8;
  s16x8 out;
  if (c0 < D) {
    s16x8 in = *(const s16x8*)(hb + (size_t)row * K1P + c0);
#pragma unroll
    for (int j = 0; j < 8; ++j) {
      int c = c0 + j;
      float v = 0.f;
      if (c < D) v = fmaxf(b2f((unsigned short)in[j]) * scale[c] + shift[c], 0.f);
      out[j] = (short)f2b(v);
    }
  } else {
#pragma unroll
    for (int j = 0; j < 8; ++j) out[j] = 0;
  }
  *(s16x8*)(r + (size_t)row * K1P + c0) = out;
}

// h = bn(hb) f32 (no relu)  [last layer]
__global__ void k_bnlast(const unsigned short* __restrict__ hb, const float* __restrict__ scale,
                         const float* __restrict__ shift, float* __restrict__ h, int total) {
  int idx = blockIdx.x * blockDim.x + threadIdx.x;
  if (idx >= total) return;
  int row = idx / 75, d = (idx - row * 75) * 4;
  s16x4 in = *(const s16x4*)(hb + (size_t)row * K1P + d);
  f32x4 v;
#pragma unroll
  for (int j = 0; j < 4; ++j)
    v[j] = b2f((unsigned short)in[j]) * scale[d + j] + shift[d + j];
  *(f32x4*)(h + (size_t)row * HP + d) = v;
}

// ---------------- outputs ----------------
__global__ void k_pool(const float* __restrict__ h, const int* __restrict__ gs,
                       const int* __restrict__ gc, float* __restrict__ pooled) {
  int g = blockIdx.x, c = threadIdx.x;
  if (c >= D) return;
  int start = gs[g], cnt = gc[g];
  float s = 0.f;
  for (int i = 0; i < cnt; ++i) s += h[(size_t)(start + i) * HP + c];
  int dv = cnt > 0 ? cnt : 1;
  pooled[(size_t)g * D + c] = s / (float)dv;
}

__global__ void k_nf(const float* __restrict__ h, const int* __restrict__ gs,
                     const int* __restrict__ gc, float* __restrict__ nf, float* __restrict__ mask) {
  int g = blockIdx.x;
  int start = gs[g], cnt = gc[g];
  int lim = cnt < MAXLEN ? cnt : MAXLEN;
  for (int idx = threadIdx.x; idx < MAXLEN * D; idx += 256) {
    int p = idx / D;
    int c = idx - p * D;
    float v = (p < lim) ? h[(size_t)(start + p) * HP + c] : 0.f;
    nf[(size_t)g * (MAXLEN * D) + idx] = v;
  }
  if (threadIdx.x < MAXLEN) mask[(size_t)g * MAXLEN + threadIdx.x] = (threadIdx.x < lim) ? 1.f : 0.f;
}

extern "C" void kernel_launch(void* const* d_in, const int* in_sizes, int n_in,
                              void* d_out, int out_size, void* d_ws, size_t ws_size,
                              hipStream_t stream) {
  const int* x      = (const int*)d_in[0];
  const int* ei     = (const int*)d_in[1];   // [2][E]: src = ei, dst = ei+E
  const int* ea     = (const int*)d_in[2];   // [E][2]
  const int* batch  = (const int*)d_in[3];
  const float* xe1  = (const float*)d_in[5];
  const float* xe2  = (const float*)d_in[6];
  const float* ee1  = (const float*)d_in[7]; // [L][6][D]
  const float* ee2  = (const float*)d_in[8]; // [L][3][D]
  const float* W1   = (const float*)d_in[9];
  const float* b1   = (const float*)d_in[10];
  const float* W2   = (const float*)d_in[11];
  const float* b2   = (const float*)d_in[12];
  const float* gamma = (const float*)d_in[13];
  const float* beta  = (const float*)d_in[14];

  const int N = in_sizes[0] / 2;
  const int E = in_sizes[1] / 2;
  const int L = in_sizes[9] / (D * 2 * D);
  const int B = out_size / (D + MAXLEN * D + MAXLEN);

  char* ws = (char*)d_ws;
  size_t off = 0;
  auto alloc = [&](size_t bytes) -> void* {
    void* p = ws + off;
    off += (bytes + 255) & ~(size_t)255;
    return p;
  };
  float* h   = (float*)alloc((size_t)N * HP * 4);
  unsigned short* r     = (unsigned short*)alloc((size_t)N * K1P * 2);
  unsigned short* aggbf = (unsigned short*)alloc((size_t)N * K1P * 2);
  unsigned short* hb    = (unsigned short*)alloc((size_t)N * K1P * 2);
  unsigned short* hid   = (unsigned short*)alloc((size_t)N * H1P * 2);
  unsigned short* W1tA = (unsigned short*)alloc((size_t)L * W1ROWS * K1P * 2);
  unsigned short* W2tA = (unsigned short*)alloc((size_t)L * W2ROWS * H1P * 2);
  float* ecomb = (float*)alloc((size_t)L * 18 * D * 4);
  int* cnt    = (int*)alloc((size_t)N * 4);
  int* cur    = (int*)alloc((size_t)N * 4);
  int* offs   = (int*)alloc((size_t)(N + 1) * 4);
  int* ssrc   = (int*)alloc((size_t)E * 4);
  int* seco   = (int*)alloc((size_t)E * 4);
  int* gc     = (int*)alloc((size_t)B * 4);
  int* gs     = (int*)alloc((size_t)(B + 1) * 4);
  float* sums  = (float*)alloc(2 * D * 4);  // sums | sumsq
  float* scale = (float*)alloc(2 * D * 4);  // scale | shift

  hipMemsetAsync(cnt, 0, (size_t)N * 4, stream);
  hipMemsetAsync(cur, 0, (size_t)N * 4, stream);
  hipMemsetAsync(gc, 0, (size_t)B * 4, stream);

  k_embed<<<(N * 75 + 255) / 256, 256, 0, stream>>>(x, xe1, xe2, r, N * 75);
  k_padfill<<<(N * 10 + 255) / 256, 256, 0, stream>>>(aggbf, N);
  k_count<<<(E + 255) / 256, 256, 0, stream>>>(ei + E, cnt, E);
  k_exscan<<<1, 1024, 0, stream>>>(cnt, offs, N);
  k_fill<<<(E + 255) / 256, 256, 0, stream>>>(ei, ei + E, ea, cur, offs, ssrc, seco, E);
  k_count<<<(N + 255) / 256, 256, 0, stream>>>(batch, gc, N);
  k_exscan<<<1, 1024, 0, stream>>>(gc, gs, B);
  k_ecomb<<<(L * 18 * D + 255) / 256, 256, 0, stream>>>(ee1, ee2, ecomb, L * 18 * D);
  for (int l = 0; l < L; ++l) {
    k_wconv<<<(W1ROWS * K1P + 255) / 256, 256, 0, stream>>>(
        W1 + (size_t)l * D * H1, W1tA + (size_t)l * W1ROWS * K1P, D, H1, K1P, W1ROWS * K1P);
    k_wconv<<<(W2ROWS * H1P + 255) / 256, 256, 0, stream>>>(
        W2 + (size_t)l * H1 * D, W2tA + (size_t)l * W2ROWS * H1P, H1, D, H1P, W2ROWS * H1P);
  }

  const int RT = (N + 127) / 128;
  for (int l = 0; l < L; ++l) {
    k_agg<<<(N + 3) / 4, 256, 0, stream>>>(r, ssrc, seco, offs,
        ecomb + (size_t)l * 18 * D, aggbf, N);
    k_gemm<K1P, 1><<<5 * RT, 256, 0, stream>>>(
        aggbf, W1tA + (size_t)l * W1ROWS * K1P, b1 + (size_t)l * H1, hid, nullptr, N, H1, H1P, 5);
    hipMemsetAsync(sums, 0, 2 * D * 4, stream);
    k_gemm<H1P, 0><<<3 * RT, 256, 0, stream>>>(
        hid, W2tA + (size_t)l * W2ROWS * H1P, b2 + (size_t)l * D, hb, sums, N, D, K1P, 3);
    k_bnfinal<<<1, 320, 0, stream>>>(sums, sums + D, gamma + (size_t)l * D, beta + (size_t)l * D,
                                     scale, scale + D, N);
    if (l != L - 1)
      k_relubn<<<(N * 40 + 255) / 256, 256, 0, stream>>>(hb, scale, scale + D, r, N * 40);
    else
      k_bnlast<<<(N * 75 + 255) / 256, 256, 0, stream>>>(hb, scale, scale + D, h, N * 75);
  }

  float* out = (float*)d_out;
  float* out_pooled = out;
  float* out_nf = out + (size_t)B * D;
  float* out_mask = out + (size_t)B * D + (size_t)B * MAXLEN * D;
  k_pool<<<B, 320, 0, stream>>>(h, gs, gc, out_pooled);
  k_nf<<<B, 256, 0, stream>>>(h, gs, gc, out_nf, out_mask);
}

// Round 6
// 2061.704 us; speedup vs baseline: 2.0872x; 1.3279x over previous
//
#include <hip/hip_runtime.h>
#include <cstdint>

#define D 300
#define MAXLEN 50
#define K1P 320    // bf16 row stride for r/aggbf/hb (640B = 10 lines); gemm1 K
#define H1 600     // hidden dim
#define H1P 608    // hid bf16 row stride (1216B); gemm2 K
#define W1ROWS 640 // padded rows for W1t (5 col-tiles of 128)
#define W2ROWS 384 // padded rows for W2t (3 col-tiles of 128)

typedef __attribute__((ext_vector_type(8))) short s16x8;
typedef __attribute__((ext_vector_type(4))) short s16x4;
typedef __attribute__((ext_vector_type(4))) float f32x4;
typedef __attribute__((ext_vector_type(2))) float f32x2;

__device__ __forceinline__ unsigned short f2b(float f) {
  uint32_t u = __builtin_bit_cast(uint32_t, f);
  u += 0x7FFFu + ((u >> 16) & 1u);
  return (unsigned short)(u >> 16);
}
__device__ __forceinline__ float b2f(unsigned short s) {
  return __builtin_bit_cast(float, (uint32_t)s << 16);
}
__device__ __forceinline__ void gld_lds16(const void* g, void* l) {
  __builtin_amdgcn_global_load_lds((const __attribute__((address_space(1))) void*)g,
                                   (__attribute__((address_space(3))) void*)l, 16, 0, 0);
}

// ---------------- embedding -> bf16 r ----------------
__global__ void k_embed(const int* __restrict__ x, const float* __restrict__ xe1,
                        const float* __restrict__ xe2, unsigned short* __restrict__ r, int total) {
  int i = blockIdx.x * blockDim.x + threadIdx.x;
  if (i >= total) return;
  int row = i / 75, d = (i - row * 75) * 4;
  int a = x[2 * row], b = x[2 * row + 1];
  s16x4 out;
#pragma unroll
  for (int j = 0; j < 4; ++j) out[j] = (short)f2b(xe1[(size_t)a * D + d + j] + xe2[(size_t)b * D + d + j]);
  *(s16x4*)(r + (size_t)row * K1P + d) = out;
}

// zero K-pad cols 300..319 of aggbf
__global__ void k_padfill(unsigned short* __restrict__ aggbf, int N) {
  int idx = blockIdx.x * blockDim.x + threadIdx.x;
  if (idx >= N * 10) return;
  int i = idx / 10, j = idx - i * 10;
  *(uint32_t*)(aggbf + (size_t)i * K1P + D + j * 2) = 0;
}

__global__ void k_count(const int* __restrict__ key, int* __restrict__ cnt, int n) {
  int i = blockIdx.x * blockDim.x + threadIdx.x;
  if (i < n) atomicAdd(&cnt[key[i]], 1);
}

__global__ void k_exscan(const int* __restrict__ in, int* __restrict__ out, int n) {
  __shared__ int smem[1024];
  int tid = threadIdx.x;
  int chunk = (n + 1023) >> 10;
  int beg = tid * chunk;
  int end = beg + chunk; if (end > n) end = n;
  int s = 0;
  for (int i = beg; i < end; ++i) s += in[i];
  smem[tid] = s;
  __syncthreads();
  for (int off = 1; off < 1024; off <<= 1) {
    int v = (tid >= off) ? smem[tid - off] : 0;
    __syncthreads();
    smem[tid] += v;
    __syncthreads();
  }
  int run = smem[tid] - s;
  for (int i = beg; i < end; ++i) { out[i] = run; run += in[i]; }
  if (tid == 1023) out[n] = smem[1023];
}

__global__ void k_fill(const int* __restrict__ src, const int* __restrict__ dst,
                       const int* __restrict__ ea, int* __restrict__ cur,
                       const int* __restrict__ offs, int* __restrict__ ssrc,
                       int* __restrict__ seco, int E_) {
  int e = blockIdx.x * blockDim.x + threadIdx.x;
  if (e >= E_) return;
  int d = dst[e];
  int p = atomicAdd(&cur[d], 1);
  int pos = offs[d] + p;
  ssrc[pos] = src[e];
  seco[pos] = ea[2 * e] * 3 + ea[2 * e + 1];
}

// combined edge-emb table: ec[l][c0*3+c1][d]
__global__ void k_ecomb(const float* __restrict__ e1, const float* __restrict__ e2,
                        float* __restrict__ ec, int total) {
  int i = blockIdx.x * blockDim.x + threadIdx.x;
  if (i >= total) return;
  int d = i % D;
  int c = (i / D) % 18;
  int l = i / (18 * D);
  int c0 = c / 3, c1 = c - c0 * 3;
  ec[i] = e1[((size_t)l * 6 + c0) * D + d] + e2[((size_t)l * 3 + c1) * D + d];
}

// ---------------- aggregation: one wave per node; 4-edge-unrolled bf16 gathers ----------------
// FUSE=1: input rows get BN scale/shift + relu applied on the fly (hin = hb of prev layer).
template <int FUSE>
__global__ void k_agg(const unsigned short* __restrict__ hin, const int* __restrict__ ssrc,
                      const int* __restrict__ seco, const int* __restrict__ offs,
                      const float* __restrict__ ec, const float* __restrict__ scale,
                      const float* __restrict__ shift, unsigned short* __restrict__ aggbf, int N) {
  int w = (int)((blockIdx.x * blockDim.x + threadIdx.x) >> 6);
  if (w >= N) return;
  int lane = threadIdx.x & 63;
  float sc0[3], sc1[3], sh0[3], sh1[3];
#pragma unroll
  for (int i = 0; i < 3; ++i) {
    int d2 = i * 64 + lane;
    if (FUSE && d2 < 150) {
      f32x2 s = *(const f32x2*)(scale + d2 * 2);
      f32x2 t = *(const f32x2*)(shift + d2 * 2);
      sc0[i] = s[0]; sc1[i] = s[1]; sh0[i] = t[0]; sh1[i] = t[1];
    } else { sc0[i] = sc1[i] = sh0[i] = sh1[i] = 0.f; }
  }
  int beg = offs[w], end = offs[w + 1];
  float s0[3], s1[3];
#pragma unroll
  for (int i = 0; i < 3; ++i) {
    int d2 = i * 64 + lane;
    float a = 0.f, b = 0.f;
    if (d2 < 150) {
      uint32_t u = *(const uint32_t*)(hin + (size_t)w * K1P + d2 * 2);
      f32x2 e = *(const f32x2*)(ec + 12 * D + d2 * 2);  // self loop combo 12
      a = b2f((unsigned short)(u & 0xFFFF));
      b = b2f((unsigned short)(u >> 16));
      if (FUSE) { a = fmaxf(a * sc0[i] + sh0[i], 0.f); b = fmaxf(b * sc1[i] + sh1[i], 0.f); }
      a += e[0]; b += e[1];
    }
    s0[i] = a; s1[i] = b;
  }
  int j = beg;
  for (; j + 4 <= end; j += 4) {
    int sv0 = ssrc[j], sv1 = ssrc[j + 1], sv2 = ssrc[j + 2], sv3 = ssrc[j + 3];
    int co0 = seco[j], co1 = seco[j + 1], co2 = seco[j + 2], co3 = seco[j + 3];
    const unsigned short* p0 = hin + (size_t)sv0 * K1P;
    const unsigned short* p1 = hin + (size_t)sv1 * K1P;
    const unsigned short* p2 = hin + (size_t)sv2 * K1P;
    const unsigned short* p3 = hin + (size_t)sv3 * K1P;
    const float* t0 = ec + (size_t)co0 * D;
    const float* t1 = ec + (size_t)co1 * D;
    const float* t2 = ec + (size_t)co2 * D;
    const float* t3 = ec + (size_t)co3 * D;
#pragma unroll
    for (int i = 0; i < 3; ++i) {
      int d2 = i * 64 + lane;
      if (d2 < 150) {
        uint32_t u0 = *(const uint32_t*)(p0 + d2 * 2);
        uint32_t u1 = *(const uint32_t*)(p1 + d2 * 2);
        uint32_t u2 = *(const uint32_t*)(p2 + d2 * 2);
        uint32_t u3 = *(const uint32_t*)(p3 + d2 * 2);
        f32x2 e0 = *(const f32x2*)(t0 + d2 * 2);
        f32x2 e1v = *(const f32x2*)(t1 + d2 * 2);
        f32x2 e2v = *(const f32x2*)(t2 + d2 * 2);
        f32x2 e3 = *(const f32x2*)(t3 + d2 * 2);
        float a0 = b2f((unsigned short)(u0 & 0xFFFF)), b0 = b2f((unsigned short)(u0 >> 16));
        float a1 = b2f((unsigned short)(u1 & 0xFFFF)), b1 = b2f((unsigned short)(u1 >> 16));
        float a2 = b2f((unsigned short)(u2 & 0xFFFF)), b2 = b2f((unsigned short)(u2 >> 16));
        float a3 = b2f((unsigned short)(u3 & 0xFFFF)), b3 = b2f((unsigned short)(u3 >> 16));
        if (FUSE) {
          a0 = fmaxf(a0 * sc0[i] + sh0[i], 0.f); b0 = fmaxf(b0 * sc1[i] + sh1[i], 0.f);
          a1 = fmaxf(a1 * sc0[i] + sh0[i], 0.f); b1 = fmaxf(b1 * sc1[i] + sh1[i], 0.f);
          a2 = fmaxf(a2 * sc0[i] + sh0[i], 0.f); b2 = fmaxf(b2 * sc1[i] + sh1[i], 0.f);
          a3 = fmaxf(a3 * sc0[i] + sh0[i], 0.f); b3 = fmaxf(b3 * sc1[i] + sh1[i], 0.f);
        }
        s0[i] += (a0 + e0[0]) + (a1 + e1v[0]) + (a2 + e2v[0]) + (a3 + e3[0]);
        s1[i] += (b0 + e0[1]) + (b1 + e1v[1]) + (b2 + e2v[1]) + (b3 + e3[1]);
      }
    }
  }
  for (; j < end; ++j) {
    int sv = ssrc[j], co = seco[j];
    const unsigned short* rp = hin + (size_t)sv * K1P;
    const float* tp = ec + (size_t)co * D;
#pragma unroll
    for (int i = 0; i < 3; ++i) {
      int d2 = i * 64 + lane;
      if (d2 < 150) {
        uint32_t u = *(const uint32_t*)(rp + d2 * 2);
        f32x2 e = *(const f32x2*)(tp + d2 * 2);
        float a = b2f((unsigned short)(u & 0xFFFF)), b = b2f((unsigned short)(u >> 16));
        if (FUSE) { a = fmaxf(a * sc0[i] + sh0[i], 0.f); b = fmaxf(b * sc1[i] + sh1[i], 0.f); }
        s0[i] += a + e[0];
        s1[i] += b + e[1];
      }
    }
  }
#pragma unroll
  for (int i = 0; i < 3; ++i) {
    int d2 = i * 64 + lane;
    if (d2 < 150) {
      uint32_t o = (uint32_t)f2b(s0[i]) | ((uint32_t)f2b(s1[i]) << 16);
      *(uint32_t*)(aggbf + (size_t)w * K1P + d2 * 2) = o;
    }
  }
}

// transpose+convert weights: Wt[n][k] = bf16(W[k][n]), zero-padded
__global__ void k_wconv(const float* __restrict__ W, unsigned short* __restrict__ Wt,
                        int K, int Nout, int Kp, int total) {
  int idx = blockIdx.x * blockDim.x + threadIdx.x;
  if (idx >= total) return;
  int n = idx / Kp, k = idx - n * Kp;
  float v = (k < K && n < Nout) ? W[(size_t)k * Nout + n] : 0.f;
  Wt[idx] = f2b(v);
}

// ---------------- 3-buffer counted-vmcnt MFMA GEMM ----------------
// 128x128 tile, 4 waves (2x2), BK=32. Stage t+2 while computing t; ONE raw
// s_barrier/iter guarded by s_waitcnt vmcnt(4) (S(t) drained, S(t+1) in flight).
// 3-buffer rotation => stage(t+2) writes a buffer whose last readers (iter t-1)
// all retired before this iter's barrier; vmcnt retires in order, so <=4
// outstanding implies S(t) complete. LDS layout XOR-swizzled (chunk ^= (row>>1)&3)
// on BOTH the global source and the ds_read (rule #21) -> conflict-free reads.
// Epilogue: direct u16 stores (L2 merges partial lines). EPI=1: relu;
// EPI=0: fused BN column stats -> atomics.
template <int K, int EPI>
__global__ __launch_bounds__(256, 3) void k_gemm(
    const unsigned short* __restrict__ A, const unsigned short* __restrict__ Bt,
    const float* __restrict__ bias, unsigned short* __restrict__ Cb,
    float* __restrict__ sums, int M, int Nout, int ldc, int CT) {
  constexpr int T = K / 32;
  __shared__ __align__(16) unsigned short smem[24576];  // 3 x (A 4096 | B 4096) shorts = 48 KB

  int nwg = gridDim.x;
  int q = nwg >> 3, r8 = nwg & 7;
  int xcd = blockIdx.x & 7, oidx = blockIdx.x >> 3;
  int wid = (xcd < r8 ? xcd * (q + 1) : r8 * (q + 1) + (xcd - r8) * q) + oidx;
  int ct = wid % CT, rt = wid / CT;
  const int rowBase = rt * 128, colBase = ct * 128;

  const int tid = threadIdx.x, lane = tid & 63, wave = tid >> 6;
  const int wm = wave >> 1, wn = wave & 1;
  const int l15 = lane & 15, lg = lane >> 4;

  unsigned short* Asm = smem;          // [3][128r][4 chunks][8]
  unsigned short* Bsm = smem + 12288;

  auto stage = [&](int s, int t) {
#pragma unroll
    for (int i = 0; i < 2; ++i) {
      int u = tid + i * 256;
      int rr = u >> 2;
      int cdat = (u & 3) ^ ((rr >> 1) & 3);  // inverse-swizzled source chunk
      int gr = rowBase + rr; if (gr >= M) gr = M - 1;
      gld_lds16(A + (size_t)gr * K + t * 32 + cdat * 8, Asm + s * 4096 + u * 8);
      gld_lds16(Bt + (size_t)(colBase + rr) * K + t * 32 + cdat * 8, Bsm + s * 4096 + u * 8);
    }
  };

  f32x4 acc[4][4] = {};
  stage(0, 0);
  stage(1, 1);
#pragma unroll
  for (int t = 0; t < T; ++t) {
    if (t + 1 < T) asm volatile("s_waitcnt vmcnt(4)" ::: "memory");
    else           asm volatile("s_waitcnt vmcnt(0)" ::: "memory");
    __builtin_amdgcn_s_barrier();
    __builtin_amdgcn_sched_barrier(0);
    const unsigned short* bA = Asm + (t % 3) * 4096;
    const unsigned short* bB = Bsm + (t % 3) * 4096;
    s16x8 af[4], bf[4];
#pragma unroll
    for (int i = 0; i < 4; ++i) {
      int ra = wm * 64 + i * 16 + l15;
      int rb = wn * 64 + i * 16 + l15;
      af[i] = *(const s16x8*)(bA + ((size_t)ra * 4 + (lg ^ ((ra >> 1) & 3))) * 8);
      bf[i] = *(const s16x8*)(bB + ((size_t)rb * 4 + (lg ^ ((rb >> 1) & 3))) * 8);
    }
    if (t + 2 < T) stage((t + 2) % 3, t + 2);
#pragma unroll
    for (int mi = 0; mi < 4; ++mi)
#pragma unroll
      for (int ni = 0; ni < 4; ++ni)
        acc[mi][ni] = __builtin_amdgcn_mfma_f32_16x16x32_bf16(af[mi], bf[ni], acc[mi][ni], 0, 0, 0);
  }

  // epilogue: direct u16 stores; pad cols [Nout, ldc) written 0 (hid K-pad for gemm2)
  float bnS[4] = {0.f, 0.f, 0.f, 0.f}, bnQ[4] = {0.f, 0.f, 0.f, 0.f};
#pragma unroll
  for (int ni = 0; ni < 4; ++ni) {
    int col = colBase + wn * 64 + ni * 16 + l15;
    if (col >= ldc) continue;
    bool inN = col < Nout;
    float bv = inN ? bias[col] : 0.f;
#pragma unroll
    for (int mi = 0; mi < 4; ++mi) {
      int row0 = rowBase + wm * 64 + mi * 16 + lg * 4;
#pragma unroll
      for (int rr = 0; rr < 4; ++rr) {
        int row = row0 + rr;
        if (row < M) {
          float v = inN ? acc[mi][ni][rr] + bv : 0.f;
          if (EPI) v = fmaxf(v, 0.f);
          else if (inN) { bnS[ni] += v; bnQ[ni] += v * v; }
          Cb[(size_t)row * ldc + col] = f2b(v);
        }
      }
    }
  }
  if (!EPI) {
#pragma unroll
    for (int ni = 0; ni < 4; ++ni) {
      float cs = bnS[ni], cq = bnQ[ni];
      cs += __shfl_xor(cs, 16); cq += __shfl_xor(cq, 16);
      cs += __shfl_xor(cs, 32); cq += __shfl_xor(cq, 32);
      int col = colBase + wn * 64 + ni * 16 + l15;
      if (lg == 0 && col < Nout) {
        atomicAdd(&sums[col], cs);
        atomicAdd(&sums[D + col], cq);
      }
    }
  }
}

// ---------------- BatchNorm finalize ----------------
__global__ void k_bnfinal(const float* __restrict__ sums, const float* __restrict__ sumsq,
                          const float* __restrict__ gamma, const float* __restrict__ beta,
                          float* __restrict__ scale, float* __restrict__ shift, int N) {
  int c = threadIdx.x;
  if (c >= D) return;
  float inv = 1.f / (float)N;
  float mean = sums[c] * inv;
  float var = sumsq[c] * inv - mean * mean;
  if (var < 0.f) var = 0.f;
  float sc = gamma[c] * rsqrtf(var + 1e-5f);
  scale[c] = sc;
  shift[c] = beta[c] - mean * sc;
}

// ---------------- outputs (BN of last layer fused; no relu) ----------------
__global__ void k_pool(const unsigned short* __restrict__ hb, const float* __restrict__ scale,
                       const float* __restrict__ shift, const int* __restrict__ gs,
                       const int* __restrict__ gc, float* __restrict__ pooled) {
  int g = blockIdx.x, c = threadIdx.x;
  if (c >= D) return;
  int start = gs[g], cnt = gc[g];
  float s = 0.f;
  for (int i = 0; i < cnt; ++i) s += b2f(hb[(size_t)(start + i) * K1P + c]);
  int dv = cnt > 0 ? cnt : 1;
  pooled[(size_t)g * D + c] = (s * scale[c] + shift[c] * (float)cnt) / (float)dv;
}

__global__ void k_nf(const unsigned short* __restrict__ hb, const float* __restrict__ scale,
                     const float* __restrict__ shift, const int* __restrict__ gs,
                     const int* __restrict__ gc, float* __restrict__ nf, float* __restrict__ mask) {
  int g = blockIdx.x;
  int start = gs[g], cnt = gc[g];
  int lim = cnt < MAXLEN ? cnt : MAXLEN;
  for (int idx = threadIdx.x; idx < MAXLEN * D; idx += 256) {
    int p = idx / D;
    int c = idx - p * D;
    float v = 0.f;
    if (p < lim) v = b2f(hb[(size_t)(start + p) * K1P + c]) * scale[c] + shift[c];
    nf[(size_t)g * (MAXLEN * D) + idx] = v;
  }
  if (threadIdx.x < MAXLEN) mask[(size_t)g * MAXLEN + threadIdx.x] = (threadIdx.x < lim) ? 1.f : 0.f;
}

extern "C" void kernel_launch(void* const* d_in, const int* in_sizes, int n_in,
                              void* d_out, int out_size, void* d_ws, size_t ws_size,
                              hipStream_t stream) {
  const int* x      = (const int*)d_in[0];
  const int* ei     = (const int*)d_in[1];   // [2][E]: src = ei, dst = ei+E
  const int* ea     = (const int*)d_in[2];   // [E][2]
  const int* batch  = (const int*)d_in[3];
  const float* xe1  = (const float*)d_in[5];
  const float* xe2  = (const float*)d_in[6];
  const float* ee1  = (const float*)d_in[7]; // [L][6][D]
  const float* ee2  = (const float*)d_in[8]; // [L][3][D]
  const float* W1   = (const float*)d_in[9];
  const float* b1   = (const float*)d_in[10];
  const float* W2   = (const float*)d_in[11];
  const float* b2   = (const float*)d_in[12];
  const float* gamma = (const float*)d_in[13];
  const float* beta  = (const float*)d_in[14];

  const int N = in_sizes[0] / 2;
  const int E = in_sizes[1] / 2;
  const int L = in_sizes[9] / (D * 2 * D);
  const int B = out_size / (D + MAXLEN * D + MAXLEN);

  char* ws = (char*)d_ws;
  size_t off = 0;
  auto alloc = [&](size_t bytes) -> void* {
    void* p = ws + off;
    off += (bytes + 255) & ~(size_t)255;
    return p;
  };
  unsigned short* r     = (unsigned short*)alloc((size_t)N * K1P * 2);
  unsigned short* aggbf = (unsigned short*)alloc((size_t)N * K1P * 2);
  unsigned short* hb    = (unsigned short*)alloc((size_t)N * K1P * 2);
  unsigned short* hid   = (unsigned short*)alloc((size_t)N * H1P * 2);
  unsigned short* W1tA = (unsigned short*)alloc((size_t)L * W1ROWS * K1P * 2);
  unsigned short* W2tA = (unsigned short*)alloc((size_t)L * W2ROWS * H1P * 2);
  float* ecomb = (float*)alloc((size_t)L * 18 * D * 4);
  int* cnt    = (int*)alloc((size_t)N * 4);
  int* cur    = (int*)alloc((size_t)N * 4);
  int* offs   = (int*)alloc((size_t)(N + 1) * 4);
  int* ssrc   = (int*)alloc((size_t)E * 4);
  int* seco   = (int*)alloc((size_t)E * 4);
  int* gc     = (int*)alloc((size_t)B * 4);
  int* gs     = (int*)alloc((size_t)(B + 1) * 4);
  float* sumsA = (float*)alloc((size_t)L * 2 * D * 4);
  float* scale = (float*)alloc(2 * D * 4);  // scale | shift

  hipMemsetAsync(cnt, 0, (size_t)N * 4, stream);
  hipMemsetAsync(cur, 0, (size_t)N * 4, stream);
  hipMemsetAsync(gc, 0, (size_t)B * 4, stream);
  hipMemsetAsync(sumsA, 0, (size_t)L * 2 * D * 4, stream);

  k_embed<<<(N * 75 + 255) / 256, 256, 0, stream>>>(x, xe1, xe2, r, N * 75);
  k_padfill<<<(N * 10 + 255) / 256, 256, 0, stream>>>(aggbf, N);
  k_count<<<(E + 255) / 256, 256, 0, stream>>>(ei + E, cnt, E);
  k_exscan<<<1, 1024, 0, stream>>>(cnt, offs, N);
  k_fill<<<(E + 255) / 256, 256, 0, stream>>>(ei, ei + E, ea, cur, offs, ssrc, seco, E);
  k_count<<<(N + 255) / 256, 256, 0, stream>>>(batch, gc, N);
  k_exscan<<<1, 1024, 0, stream>>>(gc, gs, B);
  k_ecomb<<<(L * 18 * D + 255) / 256, 256, 0, stream>>>(ee1, ee2, ecomb, L * 18 * D);
  for (int l = 0; l < L; ++l) {
    k_wconv<<<(W1ROWS * K1P + 255) / 256, 256, 0, stream>>>(
        W1 + (size_t)l * D * H1, W1tA + (size_t)l * W1ROWS * K1P, D, H1, K1P, W1ROWS * K1P);
    k_wconv<<<(W2ROWS * H1P + 255) / 256, 256, 0, stream>>>(
        W2 + (size_t)l * H1 * D, W2tA + (size_t)l * W2ROWS * H1P, H1, D, H1P, W2ROWS * H1P);
  }

  const int RT = (N + 127) / 128;
  for (int l = 0; l < L; ++l) {
    float* sums = sumsA + (size_t)l * 2 * D;
    if (l == 0)
      k_agg<0><<<(N + 3) / 4, 256, 0, stream>>>(r, ssrc, seco, offs,
          ecomb + (size_t)l * 18 * D, nullptr, nullptr, aggbf, N);
    else
      k_agg<1><<<(N + 3) / 4, 256, 0, stream>>>(hb, ssrc, seco, offs,
          ecomb + (size_t)l * 18 * D, scale, scale + D, aggbf, N);
    k_gemm<K1P, 1><<<5 * RT, 256, 0, stream>>>(
        aggbf, W1tA + (size_t)l * W1ROWS * K1P, b1 + (size_t)l * H1, hid, nullptr, N, H1, H1P, 5);
    k_gemm<H1P, 0><<<3 * RT, 256, 0, stream>>>(
        hid, W2tA + (size_t)l * W2ROWS * H1P, b2 + (size_t)l * D, hb, sums, N, D, K1P, 3);
    k_bnfinal<<<1, 320, 0, stream>>>(sums, sums + D, gamma + (size_t)l * D, beta + (size_t)l * D,
                                     scale, scale + D, N);
  }

  float* out = (float*)d_out;
  float* out_pooled = out;
  float* out_nf = out + (size_t)B * D;
  float* out_mask = out + (size_t)B * D + (size_t)B * MAXLEN * D;
  k_pool<<<B, 320, 0, stream>>>(hb, scale, scale + D, gs, gc, out_pooled);
  k_nf<<<B, 256, 0, stream>>>(hb, scale, scale + D, gs, gc, out_nf, out_mask);
}

// Round 7
// 1910.994 us; speedup vs baseline: 2.2518x; 1.0789x over previous
//
#include <hip/hip_runtime.h>
#include <cstdint>

#define D 300
#define MAXLEN 50
#define K1P 320    // bf16 row stride for r/aggbf/hb (640B = 10 lines); gemm1 K
#define H1 600     // hidden dim
#define H1P 608    // hid bf16 row stride (1216B); gemm2 K
#define W1ROWS 640 // padded rows for W1t (5 col-tiles of 128)
#define W2ROWS 384 // padded rows for W2t (3 col-tiles of 128)

typedef __attribute__((ext_vector_type(8))) short s16x8;
typedef __attribute__((ext_vector_type(4))) short s16x4;
typedef __attribute__((ext_vector_type(4))) float f32x4;
typedef __attribute__((ext_vector_type(2))) float f32x2;
typedef __attribute__((ext_vector_type(4))) int i32x4;

__device__ __forceinline__ unsigned short f2b(float f) {
  uint32_t u = __builtin_bit_cast(uint32_t, f);
  u += 0x7FFFu + ((u >> 16) & 1u);
  return (unsigned short)(u >> 16);
}
__device__ __forceinline__ float b2f(unsigned short s) {
  return __builtin_bit_cast(float, (uint32_t)s << 16);
}
__device__ __forceinline__ void gld_lds16(const void* g, void* l) {
  __builtin_amdgcn_global_load_lds((const __attribute__((address_space(1))) void*)g,
                                   (__attribute__((address_space(3))) void*)l, 16, 0, 0);
}

// ---------------- embedding -> bf16 r ----------------
__global__ void k_embed(const int* __restrict__ x, const float* __restrict__ xe1,
                        const float* __restrict__ xe2, unsigned short* __restrict__ r, int total) {
  int i = blockIdx.x * blockDim.x + threadIdx.x;
  if (i >= total) return;
  int row = i / 75, d = (i - row * 75) * 4;
  int a = x[2 * row], b = x[2 * row + 1];
  s16x4 out;
#pragma unroll
  for (int j = 0; j < 4; ++j) out[j] = (short)f2b(xe1[(size_t)a * D + d + j] + xe2[(size_t)b * D + d + j]);
  *(s16x4*)(r + (size_t)row * K1P + d) = out;
}

// zero K-pad cols 300..319 of aggbf
__global__ void k_padfill(unsigned short* __restrict__ aggbf, int N) {
  int idx = blockIdx.x * blockDim.x + threadIdx.x;
  if (idx >= N * 10) return;
  int i = idx / 10, j = idx - i * 10;
  *(uint32_t*)(aggbf + (size_t)i * K1P + D + j * 2) = 0;
}

__global__ void k_count(const int* __restrict__ key, int* __restrict__ cnt, int n) {
  int i = blockIdx.x * blockDim.x + threadIdx.x;
  if (i < n) atomicAdd(&cnt[key[i]], 1);
}

// ---------------- hierarchical exclusive scan (1024 elems/block) ----------------
__global__ void k_scan1(const int* __restrict__ in, int* __restrict__ part, int n) {
  __shared__ int red[256];
  int tid = threadIdx.x;
  int base = blockIdx.x * 1024 + tid * 4;
  i32x4 v = {0, 0, 0, 0};
  if (base + 3 < n) v = *(const i32x4*)(in + base);
  else {
#pragma unroll
    for (int k = 0; k < 4; ++k) v[k] = (base + k < n) ? in[base + k] : 0;
  }
  int s = v[0] + v[1] + v[2] + v[3];
  red[tid] = s;
  __syncthreads();
  for (int off = 1; off < 256; off <<= 1) {
    int t = (tid >= off) ? red[tid - off] : 0;
    __syncthreads();
    red[tid] += t;
    __syncthreads();
  }
  if (tid == 255) part[blockIdx.x] = red[255];
}

// single small block: exclusive scan of part[0..P), store grand total at part[P]
__global__ void k_scan2(int* __restrict__ part, int P) {
  __shared__ int sm[1024];
  int tid = threadIdx.x;
  int v = (tid < P) ? part[tid] : 0;
  sm[tid] = v;
  __syncthreads();
  for (int off = 1; off < 1024; off <<= 1) {
    int t = (tid >= off) ? sm[tid - off] : 0;
    __syncthreads();
    sm[tid] += t;
    __syncthreads();
  }
  if (tid < P) part[tid] = sm[tid] - v;
  if (tid == 1023) part[P] = sm[1023];
}

__global__ void k_scan3(const int* __restrict__ in, const int* __restrict__ part,
                        int* __restrict__ out, int n, int P) {
  __shared__ int red[256];
  int tid = threadIdx.x;
  int base = blockIdx.x * 1024 + tid * 4;
  i32x4 v = {0, 0, 0, 0};
  if (base + 3 < n) v = *(const i32x4*)(in + base);
  else {
#pragma unroll
    for (int k = 0; k < 4; ++k) v[k] = (base + k < n) ? in[base + k] : 0;
  }
  int s = v[0] + v[1] + v[2] + v[3];
  red[tid] = s;
  __syncthreads();
  for (int off = 1; off < 256; off <<= 1) {
    int t = (tid >= off) ? red[tid - off] : 0;
    __syncthreads();
    red[tid] += t;
    __syncthreads();
  }
  int pre = red[tid] - s + part[blockIdx.x];
  if (base < n) out[base] = pre;
  if (base + 1 < n) out[base + 1] = pre + v[0];
  if (base + 2 < n) out[base + 2] = pre + v[0] + v[1];
  if (base + 3 < n) out[base + 3] = pre + v[0] + v[1] + v[2];
  if (blockIdx.x == 0 && tid == 0) out[n] = part[P];
}

__global__ void k_fill(const int* __restrict__ src, const int* __restrict__ dst,
                       const int* __restrict__ ea, int* __restrict__ cur,
                       const int* __restrict__ offs, int* __restrict__ ssrc,
                       int* __restrict__ seco, int E_) {
  int e = blockIdx.x * blockDim.x + threadIdx.x;
  if (e >= E_) return;
  int d = dst[e];
  int p = atomicAdd(&cur[d], 1);
  int pos = offs[d] + p;
  ssrc[pos] = src[e];
  seco[pos] = ea[2 * e] * 3 + ea[2 * e + 1];
}

// combined edge-emb table: ec[l][c0*3+c1][d]
__global__ void k_ecomb(const float* __restrict__ e1, const float* __restrict__ e2,
                        float* __restrict__ ec, int total) {
  int i = blockIdx.x * blockDim.x + threadIdx.x;
  if (i >= total) return;
  int d = i % D;
  int c = (i / D) % 18;
  int l = i / (18 * D);
  int c0 = c / 3, c1 = c - c0 * 3;
  ec[i] = e1[((size_t)l * 6 + c0) * D + d] + e2[((size_t)l * 3 + c1) * D + d];
}

// ---------------- aggregation: one wave per node; 4-edge-unrolled bf16 gathers ----------------
// FUSE=1: input rows get BN scale/shift + relu applied on the fly (hin = hb of prev layer).
template <int FUSE>
__global__ void k_agg(const unsigned short* __restrict__ hin, const int* __restrict__ ssrc,
                      const int* __restrict__ seco, const int* __restrict__ offs,
                      const float* __restrict__ ec, const float* __restrict__ scale,
                      const float* __restrict__ shift, unsigned short* __restrict__ aggbf, int N) {
  int w = (int)((blockIdx.x * blockDim.x + threadIdx.x) >> 6);
  if (w >= N) return;
  int lane = threadIdx.x & 63;
  float sc0[3], sc1[3], sh0[3], sh1[3];
#pragma unroll
  for (int i = 0; i < 3; ++i) {
    int d2 = i * 64 + lane;
    if (FUSE && d2 < 150) {
      f32x2 s = *(const f32x2*)(scale + d2 * 2);
      f32x2 t = *(const f32x2*)(shift + d2 * 2);
      sc0[i] = s[0]; sc1[i] = s[1]; sh0[i] = t[0]; sh1[i] = t[1];
    } else { sc0[i] = sc1[i] = sh0[i] = sh1[i] = 0.f; }
  }
  int beg = offs[w], end = offs[w + 1];
  float s0[3], s1[3];
#pragma unroll
  for (int i = 0; i < 3; ++i) {
    int d2 = i * 64 + lane;
    float a = 0.f, b = 0.f;
    if (d2 < 150) {
      uint32_t u = *(const uint32_t*)(hin + (size_t)w * K1P + d2 * 2);
      f32x2 e = *(const f32x2*)(ec + 12 * D + d2 * 2);  // self loop combo 12
      a = b2f((unsigned short)(u & 0xFFFF));
      b = b2f((unsigned short)(u >> 16));
      if (FUSE) { a = fmaxf(a * sc0[i] + sh0[i], 0.f); b = fmaxf(b * sc1[i] + sh1[i], 0.f); }
      a += e[0]; b += e[1];
    }
    s0[i] = a; s1[i] = b;
  }
  int j = beg;
  for (; j + 4 <= end; j += 4) {
    int sv0 = ssrc[j], sv1 = ssrc[j + 1], sv2 = ssrc[j + 2], sv3 = ssrc[j + 3];
    int co0 = seco[j], co1 = seco[j + 1], co2 = seco[j + 2], co3 = seco[j + 3];
    const unsigned short* p0 = hin + (size_t)sv0 * K1P;
    const unsigned short* p1 = hin + (size_t)sv1 * K1P;
    const unsigned short* p2 = hin + (size_t)sv2 * K1P;
    const unsigned short* p3 = hin + (size_t)sv3 * K1P;
    const float* t0 = ec + (size_t)co0 * D;
    const float* t1 = ec + (size_t)co1 * D;
    const float* t2 = ec + (size_t)co2 * D;
    const float* t3 = ec + (size_t)co3 * D;
#pragma unroll
    for (int i = 0; i < 3; ++i) {
      int d2 = i * 64 + lane;
      if (d2 < 150) {
        uint32_t u0 = *(const uint32_t*)(p0 + d2 * 2);
        uint32_t u1 = *(const uint32_t*)(p1 + d2 * 2);
        uint32_t u2 = *(const uint32_t*)(p2 + d2 * 2);
        uint32_t u3 = *(const uint32_t*)(p3 + d2 * 2);
        f32x2 e0 = *(const f32x2*)(t0 + d2 * 2);
        f32x2 e1v = *(const f32x2*)(t1 + d2 * 2);
        f32x2 e2v = *(const f32x2*)(t2 + d2 * 2);
        f32x2 e3 = *(const f32x2*)(t3 + d2 * 2);
        float a0 = b2f((unsigned short)(u0 & 0xFFFF)), b0 = b2f((unsigned short)(u0 >> 16));
        float a1 = b2f((unsigned short)(u1 & 0xFFFF)), b1 = b2f((unsigned short)(u1 >> 16));
        float a2 = b2f((unsigned short)(u2 & 0xFFFF)), b2 = b2f((unsigned short)(u2 >> 16));
        float a3 = b2f((unsigned short)(u3 & 0xFFFF)), b3 = b2f((unsigned short)(u3 >> 16));
        if (FUSE) {
          a0 = fmaxf(a0 * sc0[i] + sh0[i], 0.f); b0 = fmaxf(b0 * sc1[i] + sh1[i], 0.f);
          a1 = fmaxf(a1 * sc0[i] + sh0[i], 0.f); b1 = fmaxf(b1 * sc1[i] + sh1[i], 0.f);
          a2 = fmaxf(a2 * sc0[i] + sh0[i], 0.f); b2 = fmaxf(b2 * sc1[i] + sh1[i], 0.f);
          a3 = fmaxf(a3 * sc0[i] + sh0[i], 0.f); b3 = fmaxf(b3 * sc1[i] + sh1[i], 0.f);
        }
        s0[i] += (a0 + e0[0]) + (a1 + e1v[0]) + (a2 + e2v[0]) + (a3 + e3[0]);
        s1[i] += (b0 + e0[1]) + (b1 + e1v[1]) + (b2 + e2v[1]) + (b3 + e3[1]);
      }
    }
  }
  for (; j < end; ++j) {
    int sv = ssrc[j], co = seco[j];
    const unsigned short* rp = hin + (size_t)sv * K1P;
    const float* tp = ec + (size_t)co * D;
#pragma unroll
    for (int i = 0; i < 3; ++i) {
      int d2 = i * 64 + lane;
      if (d2 < 150) {
        uint32_t u = *(const uint32_t*)(rp + d2 * 2);
        f32x2 e = *(const f32x2*)(tp + d2 * 2);
        float a = b2f((unsigned short)(u & 0xFFFF)), b = b2f((unsigned short)(u >> 16));
        if (FUSE) { a = fmaxf(a * sc0[i] + sh0[i], 0.f); b = fmaxf(b * sc1[i] + sh1[i], 0.f); }
        s0[i] += a + e[0];
        s1[i] += b + e[1];
      }
    }
  }
#pragma unroll
  for (int i = 0; i < 3; ++i) {
    int d2 = i * 64 + lane;
    if (d2 < 150) {
      uint32_t o = (uint32_t)f2b(s0[i]) | ((uint32_t)f2b(s1[i]) << 16);
      *(uint32_t*)(aggbf + (size_t)w * K1P + d2 * 2) = o;
    }
  }
}

// transpose+convert weights: Wt[n][k] = bf16(W[k][n]), zero-padded
__global__ void k_wconv(const float* __restrict__ W, unsigned short* __restrict__ Wt,
                        int K, int Nout, int Kp, int total) {
  int idx = blockIdx.x * blockDim.x + threadIdx.x;
  if (idx >= total) return;
  int n = idx / Kp, k = idx - n * Kp;
  float v = (k < K && n < Nout) ? W[(size_t)k * Nout + n] : 0.f;
  Wt[idx] = f2b(v);
}

// ---------------- 3-buffer counted-vmcnt MFMA GEMM ----------------
// 128x128 tile, 4 waves (2x2), BK=32. Stage t+2 while computing t; ONE raw
// s_barrier/iter guarded by s_waitcnt vmcnt(4) (S(t) drained, S(t+1) in flight).
// 3-buffer rotation => stage(t+2) writes a buffer whose last readers (iter t-1)
// all retired before this iter's barrier; vmcnt retires in order, so <=4
// outstanding implies S(t) complete. LDS layout XOR-swizzled (chunk ^= (row>>1)&3)
// on BOTH the global source and the ds_read (rule #21) -> conflict-free reads.
// Epilogue: direct u16 stores (L2 merges partial lines). EPI=1: relu;
// EPI=0: fused BN column stats -> atomics.
template <int K, int EPI>
__global__ __launch_bounds__(256, 3) void k_gemm(
    const unsigned short* __restrict__ A, const unsigned short* __restrict__ Bt,
    const float* __restrict__ bias, unsigned short* __restrict__ Cb,
    float* __restrict__ sums, int M, int Nout, int ldc, int CT) {
  constexpr int T = K / 32;
  __shared__ __align__(16) unsigned short smem[24576];  // 3 x (A 4096 | B 4096) shorts = 48 KB

  int nwg = gridDim.x;
  int q = nwg >> 3, r8 = nwg & 7;
  int xcd = blockIdx.x & 7, oidx = blockIdx.x >> 3;
  int wid = (xcd < r8 ? xcd * (q + 1) : r8 * (q + 1) + (xcd - r8) * q) + oidx;
  int ct = wid % CT, rt = wid / CT;
  const int rowBase = rt * 128, colBase = ct * 128;

  const int tid = threadIdx.x, lane = tid & 63, wave = tid >> 6;
  const int wm = wave >> 1, wn = wave & 1;
  const int l15 = lane & 15, lg = lane >> 4;

  unsigned short* Asm = smem;          // [3][128r][4 chunks][8]
  unsigned short* Bsm = smem + 12288;

  auto stage = [&](int s, int t) {
#pragma unroll
    for (int i = 0; i < 2; ++i) {
      int u = tid + i * 256;
      int rr = u >> 2;
      int cdat = (u & 3) ^ ((rr >> 1) & 3);  // inverse-swizzled source chunk
      int gr = rowBase + rr; if (gr >= M) gr = M - 1;
      gld_lds16(A + (size_t)gr * K + t * 32 + cdat * 8, Asm + s * 4096 + u * 8);
      gld_lds16(Bt + (size_t)(colBase + rr) * K + t * 32 + cdat * 8, Bsm + s * 4096 + u * 8);
    }
  };

  f32x4 acc[4][4] = {};
  stage(0, 0);
  stage(1, 1);
#pragma unroll
  for (int t = 0; t < T; ++t) {
    if (t + 1 < T) asm volatile("s_waitcnt vmcnt(4)" ::: "memory");
    else           asm volatile("s_waitcnt vmcnt(0)" ::: "memory");
    __builtin_amdgcn_s_barrier();
    __builtin_amdgcn_sched_barrier(0);
    const unsigned short* bA = Asm + (t % 3) * 4096;
    const unsigned short* bB = Bsm + (t % 3) * 4096;
    s16x8 af[4], bf[4];
#pragma unroll
    for (int i = 0; i < 4; ++i) {
      int ra = wm * 64 + i * 16 + l15;
      int rb = wn * 64 + i * 16 + l15;
      af[i] = *(const s16x8*)(bA + ((size_t)ra * 4 + (lg ^ ((ra >> 1) & 3))) * 8);
      bf[i] = *(const s16x8*)(bB + ((size_t)rb * 4 + (lg ^ ((rb >> 1) & 3))) * 8);
    }
    if (t + 2 < T) stage((t + 2) % 3, t + 2);
#pragma unroll
    for (int mi = 0; mi < 4; ++mi)
#pragma unroll
      for (int ni = 0; ni < 4; ++ni)
        acc[mi][ni] = __builtin_amdgcn_mfma_f32_16x16x32_bf16(af[mi], bf[ni], acc[mi][ni], 0, 0, 0);
  }

  // epilogue: direct u16 stores; pad cols [Nout, ldc) written 0 (hid K-pad for gemm2)
  float bnS[4] = {0.f, 0.f, 0.f, 0.f}, bnQ[4] = {0.f, 0.f, 0.f, 0.f};
#pragma unroll
  for (int ni = 0; ni < 4; ++ni) {
    int col = colBase + wn * 64 + ni * 16 + l15;
    if (col >= ldc) continue;
    bool inN = col < Nout;
    float bv = inN ? bias[col] : 0.f;
#pragma unroll
    for (int mi = 0; mi < 4; ++mi) {
      int row0 = rowBase + wm * 64 + mi * 16 + lg * 4;
#pragma unroll
      for (int rr = 0; rr < 4; ++rr) {
        int row = row0 + rr;
        if (row < M) {
          float v = inN ? acc[mi][ni][rr] + bv : 0.f;
          if (EPI) v = fmaxf(v, 0.f);
          else if (inN) { bnS[ni] += v; bnQ[ni] += v * v; }
          Cb[(size_t)row * ldc + col] = f2b(v);
        }
      }
    }
  }
  if (!EPI) {
#pragma unroll
    for (int ni = 0; ni < 4; ++ni) {
      float cs = bnS[ni], cq = bnQ[ni];
      cs += __shfl_xor(cs, 16); cq += __shfl_xor(cq, 16);
      cs += __shfl_xor(cs, 32); cq += __shfl_xor(cq, 32);
      int col = colBase + wn * 64 + ni * 16 + l15;
      if (lg == 0 && col < Nout) {
        atomicAdd(&sums[col], cs);
        atomicAdd(&sums[D + col], cq);
      }
    }
  }
}

// ---------------- BatchNorm finalize ----------------
__global__ void k_bnfinal(const float* __restrict__ sums, const float* __restrict__ sumsq,
                          const float* __restrict__ gamma, const float* __restrict__ beta,
                          float* __restrict__ scale, float* __restrict__ shift, int N) {
  int c = threadIdx.x;
  if (c >= D) return;
  float inv = 1.f / (float)N;
  float mean = sums[c] * inv;
  float var = sumsq[c] * inv - mean * mean;
  if (var < 0.f) var = 0.f;
  float sc = gamma[c] * rsqrtf(var + 1e-5f);
  scale[c] = sc;
  shift[c] = beta[c] - mean * sc;
}

// ---------------- outputs (BN of last layer fused; no relu) ----------------
__global__ void k_pool(const unsigned short* __restrict__ hb, const float* __restrict__ scale,
                       const float* __restrict__ shift, const int* __restrict__ gs,
                       const int* __restrict__ gc, float* __restrict__ pooled) {
  int g = blockIdx.x, c = threadIdx.x;
  if (c >= D) return;
  int start = gs[g], cnt = gc[g];
  float s = 0.f;
  for (int i = 0; i < cnt; ++i) s += b2f(hb[(size_t)(start + i) * K1P + c]);
  int dv = cnt > 0 ? cnt : 1;
  pooled[(size_t)g * D + c] = (s * scale[c] + shift[c] * (float)cnt) / (float)dv;
}

__global__ void k_nf(const unsigned short* __restrict__ hb, const float* __restrict__ scale,
                     const float* __restrict__ shift, const int* __restrict__ gs,
                     const int* __restrict__ gc, float* __restrict__ nf, float* __restrict__ mask) {
  int g = blockIdx.x;
  int start = gs[g], cnt = gc[g];
  int lim = cnt < MAXLEN ? cnt : MAXLEN;
  for (int idx = threadIdx.x; idx < MAXLEN * D; idx += 256) {
    int p = idx / D;
    int c = idx - p * D;
    float v = 0.f;
    if (p < lim) v = b2f(hb[(size_t)(start + p) * K1P + c]) * scale[c] + shift[c];
    nf[(size_t)g * (MAXLEN * D) + idx] = v;
  }
  if (threadIdx.x < MAXLEN) mask[(size_t)g * MAXLEN + threadIdx.x] = (threadIdx.x < lim) ? 1.f : 0.f;
}

extern "C" void kernel_launch(void* const* d_in, const int* in_sizes, int n_in,
                              void* d_out, int out_size, void* d_ws, size_t ws_size,
                              hipStream_t stream) {
  const int* x      = (const int*)d_in[0];
  const int* ei     = (const int*)d_in[1];   // [2][E]: src = ei, dst = ei+E
  const int* ea     = (const int*)d_in[2];   // [E][2]
  const int* batch  = (const int*)d_in[3];
  const float* xe1  = (const float*)d_in[5];
  const float* xe2  = (const float*)d_in[6];
  const float* ee1  = (const float*)d_in[7]; // [L][6][D]
  const float* ee2  = (const float*)d_in[8]; // [L][3][D]
  const float* W1   = (const float*)d_in[9];
  const float* b1   = (const float*)d_in[10];
  const float* W2   = (const float*)d_in[11];
  const float* b2   = (const float*)d_in[12];
  const float* gamma = (const float*)d_in[13];
  const float* beta  = (const float*)d_in[14];

  const int N = in_sizes[0] / 2;
  const int E = in_sizes[1] / 2;
  const int L = in_sizes[9] / (D * 2 * D);
  const int B = out_size / (D + MAXLEN * D + MAXLEN);

  char* ws = (char*)d_ws;
  size_t off = 0;
  auto alloc = [&](size_t bytes) -> void* {
    void* p = ws + off;
    off += (bytes + 255) & ~(size_t)255;
    return p;
  };
  unsigned short* r     = (unsigned short*)alloc((size_t)N * K1P * 2);
  unsigned short* aggbf = (unsigned short*)alloc((size_t)N * K1P * 2);
  unsigned short* hb    = (unsigned short*)alloc((size_t)N * K1P * 2);
  unsigned short* hid   = (unsigned short*)alloc((size_t)N * H1P * 2);
  unsigned short* W1tA = (unsigned short*)alloc((size_t)L * W1ROWS * K1P * 2);
  unsigned short* W2tA = (unsigned short*)alloc((size_t)L * W2ROWS * H1P * 2);
  float* ecomb = (float*)alloc((size_t)L * 18 * D * 4);
  int* cnt    = (int*)alloc((size_t)N * 4);
  int* cur    = (int*)alloc((size_t)N * 4);
  int* offs   = (int*)alloc((size_t)(N + 1) * 4);
  int* ssrc   = (int*)alloc((size_t)E * 4);
  int* seco   = (int*)alloc((size_t)E * 4);
  int* gc     = (int*)alloc((size_t)B * 4);
  int* gs     = (int*)alloc((size_t)(B + 1) * 4);
  int* part   = (int*)alloc(1024 * 4);
  float* sumsA = (float*)alloc((size_t)L * 2 * D * 4);
  float* scale = (float*)alloc(2 * D * 4);  // scale | shift

  hipMemsetAsync(cnt, 0, (size_t)N * 4, stream);
  hipMemsetAsync(cur, 0, (size_t)N * 4, stream);
  hipMemsetAsync(gc, 0, (size_t)B * 4, stream);
  hipMemsetAsync(sumsA, 0, (size_t)L * 2 * D * 4, stream);

  k_embed<<<(N * 75 + 255) / 256, 256, 0, stream>>>(x, xe1, xe2, r, N * 75);
  k_padfill<<<(N * 10 + 255) / 256, 256, 0, stream>>>(aggbf, N);
  k_count<<<(E + 255) / 256, 256, 0, stream>>>(ei + E, cnt, E);
  {
    int P = (N + 1023) / 1024;
    k_scan1<<<P, 256, 0, stream>>>(cnt, part, N);
    k_scan2<<<1, 1024, 0, stream>>>(part, P);
    k_scan3<<<P, 256, 0, stream>>>(cnt, part, offs, N, P);
  }
  k_fill<<<(E + 255) / 256, 256, 0, stream>>>(ei, ei + E, ea, cur, offs, ssrc, seco, E);
  k_count<<<(N + 255) / 256, 256, 0, stream>>>(batch, gc, N);
  {
    int P = (B + 1023) / 1024;
    k_scan1<<<P, 256, 0, stream>>>(gc, part, B);
    k_scan2<<<1, 1024, 0, stream>>>(part, P);
    k_scan3<<<P, 256, 0, stream>>>(gc, part, gs, B, P);
  }
  k_ecomb<<<(L * 18 * D + 255) / 256, 256, 0, stream>>>(ee1, ee2, ecomb, L * 18 * D);
  for (int l = 0; l < L; ++l) {
    k_wconv<<<(W1ROWS * K1P + 255) / 256, 256, 0, stream>>>(
        W1 + (size_t)l * D * H1, W1tA + (size_t)l * W1ROWS * K1P, D, H1, K1P, W1ROWS * K1P);
    k_wconv<<<(W2ROWS * H1P + 255) / 256, 256, 0, stream>>>(
        W2 + (size_t)l * H1 * D, W2tA + (size_t)l * W2ROWS * H1P, H1, D, H1P, W2ROWS * H1P);
  }

  const int RT = (N + 127) / 128;
  for (int l = 0; l < L; ++l) {
    float* sums = sumsA + (size_t)l * 2 * D;
    if (l == 0)
      k_agg<0><<<(N + 3) / 4, 256, 0, stream>>>(r, ssrc, seco, offs,
          ecomb + (size_t)l * 18 * D, nullptr, nullptr, aggbf, N);
    else
      k_agg<1><<<(N + 3) / 4, 256, 0, stream>>>(hb, ssrc, seco, offs,
          ecomb + (size_t)l * 18 * D, scale, scale + D, aggbf, N);
    k_gemm<K1P, 1><<<5 * RT, 256, 0, stream>>>(
        aggbf, W1tA + (size_t)l * W1ROWS * K1P, b1 + (size_t)l * H1, hid, nullptr, N, H1, H1P, 5);
    k_gemm<H1P, 0><<<3 * RT, 256, 0, stream>>>(
        hid, W2tA + (size_t)l * W2ROWS * H1P, b2 + (size_t)l * D, hb, sums, N, D, K1P, 3);
    k_bnfinal<<<1, 320, 0, stream>>>(sums, sums + D, gamma + (size_t)l * D, beta + (size_t)l * D,
                                     scale, scale + D, N);
  }

  float* out = (float*)d_out;
  float* out_pooled = out;
  float* out_nf = out + (size_t)B * D;
  float* out_mask = out + (size_t)B * D + (size_t)B * MAXLEN * D;
  k_pool<<<B, 320, 0, stream>>>(hb, scale, scale + D, gs, gc, out_pooled);
  k_nf<<<B, 256, 0, stream>>>(hb, scale, scale + D, gs, gc, out_nf, out_mask);
}